// Round 8
// baseline (143.505 us; speedup 1.0000x reference)
//
#include <hip/hip_runtime.h>

#define NB 32      // batch
#define NJ 8192    // h*w*Nin
#define NC 10      // NUM_CAPS
#define CL 16      // CAP_LEN
#define KK 160     // NC*CL
#define JT 16      // j per block
#define NTHR 640   // 40 k4 x 16 jj  (t = k4*16 + jj)
#define BCH 8      // batches per barrier pair (4 chunks)
#define NPART (NJ / JT)   // 512 partial slots along j
#define EPSQ 1e-20f

// in-wave sum over jj = lane&15, pure VALU via DPP adds
template<int CTRL>
__device__ __forceinline__ float dpp_add(float v) {
    int s = __builtin_amdgcn_update_dpp(0, __float_as_int(v), CTRL, 0xF, 0xF, true);
    return v + __int_as_float(s);
}
__device__ __forceinline__ float red16(float v) {
    v = dpp_add<0xB1>(v);    // quad_perm xor1
    v = dpp_add<0x4E>(v);    // quad_perm xor2
    v = dpp_add<0x141>(v);   // row_half_mirror
    v = dpp_add<0x140>(v);   // row_mirror
    return v;
}

// One routing iteration. W in registers (32 VGPR), u in registers,
// j-reduce via DPP, partials stored (no global atomics).
// DS-diet version: xs b128 reads (pad 12), vsum from global (no vsl),
// softmax by 2 waves only, BCH=8 (8 barriers/rout).
// Linearity trick: logits b_r[b,j,n] = u . (v0+...+v_{r-1}) -> carry only vsum.
template<int R>
__global__ __launch_bounds__(NTHR, 5)
void rout_kernel(const float* __restrict__ x, const float* __restrict__ W,
                 const float* __restrict__ vsum, float* __restrict__ part) {
    __shared__ float xs[NB][JT][12];   // 24 KB, pad 12 -> aligned b128 rows
    __shared__ float bl[BCH][JT][13];  // 6.5 KB, pad 13 -> conflict-free b32
    __shared__ float cl[BCH][JT][13];  // 6.5 KB

    const int t   = threadIdx.x;
    const int jj  = t & 15;            // j within tile (lane bits 0..3)
    const int k4  = t >> 4;            // float4 chunk of k, 0..39
    const int nB  = k4 >> 2;           // cap index (= wave index)
    const int c4  = k4 & 3;            // c-quad within cap (lane bits 4,5)
    const int j0  = blockIdx.x * JT;

    // ---- W -> registers, once ----
    float4 w[8];
    {
        const float* wp = W + ((size_t)(j0 + jj) * 8) * KK + (k4 << 2);
        #pragma unroll
        for (int i = 0; i < 8; ++i)
            w[i] = *(const float4*)(wp + i * KK);
    }
    // ---- x tile -> LDS (f4 writes into 12-padded rows) ----
    for (int e4 = t; e4 < NB * JT * 2; e4 += NTHR) {
        const int b = e4 >> 5, rem = e4 & 31, jx = rem >> 1, hf = rem & 1;
        *(float4*)&xs[b][jx][hf * 4] =
            *(const float4*)(x + ((size_t)b * NJ + j0 + jx) * 8 + hf * 4);
    }
    __syncthreads();

    #pragma unroll 1
    for (int b0 = 0; b0 < NB; b0 += BCH) {
        float4 u[BCH];
        // ---- A (+B): u quads in registers; logit partial + reduce ----
        #pragma unroll
        for (int bc = 0; bc < BCH; ++bc) {
            const float4 xa = *(const float4*)&xs[b0 + bc][jj][0];
            const float4 xb = *(const float4*)&xs[b0 + bc][jj][4];
            float4 acc = {0.f, 0.f, 0.f, 0.f};
            acc.x = fmaf(w[0].x, xa.x, acc.x); acc.y = fmaf(w[0].y, xa.x, acc.y);
            acc.z = fmaf(w[0].z, xa.x, acc.z); acc.w = fmaf(w[0].w, xa.x, acc.w);
            acc.x = fmaf(w[1].x, xa.y, acc.x); acc.y = fmaf(w[1].y, xa.y, acc.y);
            acc.z = fmaf(w[1].z, xa.y, acc.z); acc.w = fmaf(w[1].w, xa.y, acc.w);
            acc.x = fmaf(w[2].x, xa.z, acc.x); acc.y = fmaf(w[2].y, xa.z, acc.y);
            acc.z = fmaf(w[2].z, xa.z, acc.z); acc.w = fmaf(w[2].w, xa.z, acc.w);
            acc.x = fmaf(w[3].x, xa.w, acc.x); acc.y = fmaf(w[3].y, xa.w, acc.y);
            acc.z = fmaf(w[3].z, xa.w, acc.z); acc.w = fmaf(w[3].w, xa.w, acc.w);
            acc.x = fmaf(w[4].x, xb.x, acc.x); acc.y = fmaf(w[4].y, xb.x, acc.y);
            acc.z = fmaf(w[4].z, xb.x, acc.z); acc.w = fmaf(w[4].w, xb.x, acc.w);
            acc.x = fmaf(w[5].x, xb.y, acc.x); acc.y = fmaf(w[5].y, xb.y, acc.y);
            acc.z = fmaf(w[5].z, xb.y, acc.z); acc.w = fmaf(w[5].w, xb.y, acc.w);
            acc.x = fmaf(w[6].x, xb.z, acc.x); acc.y = fmaf(w[6].y, xb.z, acc.y);
            acc.z = fmaf(w[6].z, xb.z, acc.z); acc.w = fmaf(w[6].w, xb.z, acc.w);
            acc.x = fmaf(w[7].x, xb.w, acc.x); acc.y = fmaf(w[7].y, xb.w, acc.y);
            acc.z = fmaf(w[7].z, xb.w, acc.z); acc.w = fmaf(w[7].w, xb.w, acc.w);
            u[bc] = acc;

            if (R > 0) {
                // logit = u . vsum (global read: L1-hot, 16-lane-uniform f4)
                const float4 vv = *(const float4*)(vsum + (size_t)(b0 + bc) * KK + (k4 << 2));
                float bd = u[bc].x * vv.x;
                bd = fmaf(u[bc].y, vv.y, bd);
                bd = fmaf(u[bc].z, vv.z, bd);
                bd = fmaf(u[bc].w, vv.w, bd);
                bd += __shfl_xor(bd, 16);   // sum the 4 c-quads of cap nB
                bd += __shfl_xor(bd, 32);
                if (c4 == 0) bl[bc][jj][nB] = bd;
            }
        }

        if (R > 0) {
            __syncthreads();
            // ---- C: softmax over n, NON-REDUNDANT: 128 threads = 8bc x 16jj ----
            if (t < BCH * JT) {
                const int bcC = t >> 4, jjC = t & 15;
                float lg[NC];
                #pragma unroll
                for (int q = 0; q < NC; ++q) lg[q] = bl[bcC][jjC][q];
                float m = lg[0];
                #pragma unroll
                for (int q = 1; q < NC; ++q) m = fmaxf(m, lg[q]);
                float sum = 0.f;
                #pragma unroll
                for (int q = 0; q < NC; ++q) { lg[q] = __expf(lg[q] - m); sum += lg[q]; }
                const float inv = 1.f / sum;
                #pragma unroll
                for (int q = 0; q < NC; ++q) cl[bcC][jjC][q] = lg[q] * inv;
            }
            __syncthreads();
        }

        // ---- D: s partial = sum_jj c*u via DPP, one f4 store per (b,k4) ----
        #pragma unroll
        for (int bc = 0; bc < BCH; ++bc) {
            const int b = b0 + bc;
            const float c = (R == 0) ? 0.1f : cl[bc][jj][nB];
            const float sx = red16(u[bc].x * c);
            const float sy = red16(u[bc].y * c);
            const float sz = red16(u[bc].z * c);
            const float sw = red16(u[bc].w * c);
            if (jj == 0) {
                float4 q; q.x = sx; q.y = sy; q.z = sz; q.w = sw;
                *(float4*)(part + ((size_t)blockIdx.x * NB + b) * KK + (k4 << 2)) = q;
            }
        }
    }
}

// Sum NPART partials (coalesced), +bias, squash.
// MODE: 0 vsum=v, 1 vsum+=v, 2 out=v. Grid: 20 blocks x 1024 threads.
template<int MODE>
__global__ __launch_bounds__(1024)
void reduce_squash(const float* __restrict__ part, const float* __restrict__ biases,
                   float* __restrict__ vsum, float* __restrict__ out) {
    __shared__ float4 red[16][64];     // 16 KB
    const int t   = threadIdx.x;
    const int col = t & 63;
    const int pc  = t >> 6;
    const int g   = blockIdx.x * 64 + col;   // global f4 index, 0..1279
    const float4* p4 = (const float4*)part;

    float4 acc = {0.f, 0.f, 0.f, 0.f};
    #pragma unroll 4
    for (int p = pc * 32; p < pc * 32 + 32; ++p) {
        const float4 v = p4[(size_t)p * (NB * KK / 4) + g];
        acc.x += v.x; acc.y += v.y; acc.z += v.z; acc.w += v.w;
    }
    red[pc][col] = acc;
    __syncthreads();
    if (pc == 0) {
        #pragma unroll
        for (int q = 1; q < 16; ++q) {
            const float4 v = red[q][col];
            acc.x += v.x; acc.y += v.y; acc.z += v.z; acc.w += v.w;
        }
        const int k4 = g % 40;
        const float4 bb = *(const float4*)(biases + k4 * 4);
        float4 v;
        {
            const float s0 = acc.x + bb.x, n0 = fabsf(s0);
            v.x = (n0 * n0) / (1.f + n0 * n0) / (n0 + EPSQ) * s0;
            const float s1 = acc.y + bb.y, n1 = fabsf(s1);
            v.y = (n1 * n1) / (1.f + n1 * n1) / (n1 + EPSQ) * s1;
            const float s2 = acc.z + bb.z, n2 = fabsf(s2);
            v.z = (n2 * n2) / (1.f + n2 * n2) / (n2 + EPSQ) * s2;
            const float s3 = acc.w + bb.w, n3 = fabsf(s3);
            v.w = (n3 * n3) / (1.f + n3 * n3) / (n3 + EPSQ) * s3;
        }
        if (MODE == 2) {
            ((float4*)out)[g] = v;
        } else if (MODE == 1) {
            float4 o = ((float4*)vsum)[g];
            o.x += v.x; o.y += v.y; o.z += v.z; o.w += v.w;
            ((float4*)vsum)[g] = o;
        } else {
            ((float4*)vsum)[g] = v;
        }
    }
}

extern "C" void kernel_launch(void* const* d_in, const int* in_sizes, int n_in,
                              void* d_out, int out_size, void* d_ws, size_t ws_size,
                              hipStream_t stream) {
    const float* x      = (const float*)d_in[0];
    const float* W      = (const float*)d_in[1];
    const float* biases = (const float*)d_in[2];
    float* out  = (float*)d_out;
    float* part = (float*)d_ws;                        // [NPART][NB*KK]
    float* vsum = part + (size_t)NPART * NB * KK;      // [NB*KK]

    const dim3 grid(NJ / JT);   // 512 blocks (2/CU)

    rout_kernel<0><<<grid, NTHR, 0, stream>>>(x, W, nullptr, part);
    reduce_squash<0><<<20, 1024, 0, stream>>>(part, biases, vsum, out);

    rout_kernel<1><<<grid, NTHR, 0, stream>>>(x, W, vsum, part);
    reduce_squash<1><<<20, 1024, 0, stream>>>(part, biases, vsum, out);

    rout_kernel<2><<<grid, NTHR, 0, stream>>>(x, W, vsum, part);
    reduce_squash<2><<<20, 1024, 0, stream>>>(part, biases, vsum, out);
}